// Round 1
// baseline (2136.267 us; speedup 1.0000x reference)
//
#include <hip/hip_runtime.h>
#include <math.h>

#define NN 100000
#define NE 1600000
#define HD 32
#define NG 64
#define NC 8

// ---------- graph normalization ----------
__global__ __launch_bounds__(256) void k_deg_init(float* deg) {
    int i = blockIdx.x * 256 + threadIdx.x;
    if (i < NN) deg[i] = 1.0f;  // self-loop weight
}

__global__ __launch_bounds__(256) void k_deg_acc(const int* __restrict__ col,
                                                 const float* __restrict__ w,
                                                 float* deg) {
    int e = blockIdx.x * 256 + threadIdx.x;
    if (e < NE) atomicAdd(&deg[col[e]], w[e]);
}

__global__ __launch_bounds__(256) void k_dinv(float* deg) {
    int i = blockIdx.x * 256 + threadIdx.x;
    if (i < NN) { float d = deg[i]; deg[i] = d > 0.0f ? rsqrtf(d) : 0.0f; }
}

__global__ __launch_bounds__(256) void k_norm(const int* __restrict__ row,
                                              const int* __restrict__ col,
                                              const float* __restrict__ w,
                                              const float* __restrict__ dinv,
                                              float* __restrict__ nrm) {
    int e = blockIdx.x * 256 + threadIdx.x;
    if (e < NE) nrm[e] = dinv[row[e]] * w[e] * dinv[col[e]];
}

// ---------- feature transform: out = act(in) @ W ----------
// act(in) = relu(in + bprev) when PREACT (fuses previous layer's bias+relu)
template <bool PREACT>
__global__ __launch_bounds__(256) void k_gemm(const float* __restrict__ in,
                                              const float* __restrict__ Wm,
                                              const float* __restrict__ bprev,
                                              float* __restrict__ out) {
    __shared__ float sW[32 * 32];
    __shared__ float sX[8 * 32];
    int tid = threadIdx.x;
    int base = blockIdx.x * 8;  // 8 nodes per block, N divisible by 8
    ((float4*)sW)[tid] = ((const float4*)Wm)[tid];  // 256 * float4 = 1024 floats
    if (tid < 64) {
        float4 v = ((const float4*)(in + base * 32))[tid];
        if (PREACT) {
            int k4 = (tid & 7) * 4;
            v.x = fmaxf(v.x + bprev[k4 + 0], 0.0f);
            v.y = fmaxf(v.y + bprev[k4 + 1], 0.0f);
            v.z = fmaxf(v.z + bprev[k4 + 2], 0.0f);
            v.w = fmaxf(v.w + bprev[k4 + 3], 0.0f);
        }
        ((float4*)sX)[tid] = v;
    }
    __syncthreads();
    int c = tid & 31, nl = tid >> 5;
    float acc = 0.0f;
#pragma unroll
    for (int k = 0; k < 32; ++k) acc = fmaf(sX[nl * 32 + k], sW[k * 32 + c], acc);
    out[(base + nl) * 32 + c] = acc;
}

// ---------- self-loop term doubles as agg initialization ----------
__global__ __launch_bounds__(256) void k_selfloop(const float* __restrict__ h,
                                                  const float* __restrict__ dinv,
                                                  float* __restrict__ agg) {
    int t = blockIdx.x * 256 + threadIdx.x;  // over N*32
    int n = t >> 5;
    float di = dinv[n];
    agg[t] = di * di * h[t];
}

// ---------- edge scatter: agg[col] += norm * h[row] ----------
__global__ __launch_bounds__(256) void k_scatter(const int* __restrict__ row,
                                                 const int* __restrict__ col,
                                                 const float* __restrict__ nrm,
                                                 const float* __restrict__ h,
                                                 float* __restrict__ agg) {
    unsigned t = blockIdx.x * 256 + threadIdx.x;  // e*8 + q
    unsigned e = t >> 3;
    if (e >= NE) return;
    int q = t & 7;
    float nm = nrm[e];
    int r = row[e], ci = col[e];
    float4 hv = ((const float4*)(h + r * 32))[q];
    float* dst = agg + ci * 32 + q * 4;
    atomicAdd(dst + 0, nm * hv.x);
    atomicAdd(dst + 1, nm * hv.y);
    atomicAdd(dst + 2, nm * hv.z);
    atomicAdd(dst + 3, nm * hv.w);
}

// ---------- global mean pool + linear head + log_softmax ----------
__global__ __launch_bounds__(1024) void k_pool_head(const float* __restrict__ agg3,
                                                    const float* __restrict__ b3,
                                                    const int* __restrict__ batch,
                                                    const float* __restrict__ Wout,
                                                    const float* __restrict__ bout,
                                                    float* __restrict__ out) {
    int g = blockIdx.x;
    __shared__ int sb[2];
    if (threadIdx.x == 0) {
        int lo = 0, hi = NN;
        while (lo < hi) { int m = (lo + hi) >> 1; if (batch[m] < g) lo = m + 1; else hi = m; }
        sb[0] = lo;
        lo = 0; hi = NN;
        while (lo < hi) { int m = (lo + hi) >> 1; if (batch[m] < g + 1) lo = m + 1; else hi = m; }
        sb[1] = lo;
    }
    __syncthreads();
    int start = sb[0], end = sb[1];
    int c = threadIdx.x & 31, grp = threadIdx.x >> 5;  // 32 groups of 32 channels
    float bc = b3[c];
    float acc = 0.0f;
    for (int n = start + grp; n < end; n += 32)
        acc += fmaxf(agg3[n * 32 + c] + bc, 0.0f);
    __shared__ float red[32 * 32];
    red[grp * 32 + c] = acc;
    __syncthreads();
    __shared__ float pooled[32];
    if (threadIdx.x < 32) {
        float s = 0.0f;
#pragma unroll
        for (int gr = 0; gr < 32; ++gr) s += red[gr * 32 + threadIdx.x];
        pooled[threadIdx.x] = s / fmaxf((float)(end - start), 1.0f);
    }
    __syncthreads();
    __shared__ float slog[8];
    if (threadIdx.x < 8) {
        float l = bout[threadIdx.x];
#pragma unroll
        for (int k = 0; k < 32; ++k) l = fmaf(pooled[k], Wout[k * 8 + threadIdx.x], l);
        slog[threadIdx.x] = l;
    }
    __syncthreads();
    if (threadIdx.x < 8) {
        float m = slog[0];
#pragma unroll
        for (int i = 1; i < 8; ++i) m = fmaxf(m, slog[i]);
        float s = 0.0f;
#pragma unroll
        for (int i = 0; i < 8; ++i) s += expf(slog[i] - m);
        out[g * NC + threadIdx.x] = slog[threadIdx.x] - m - logf(s);
    }
}

extern "C" void kernel_launch(void* const* d_in, const int* in_sizes, int n_in,
                              void* d_out, int out_size, void* d_ws, size_t ws_size,
                              hipStream_t stream) {
    const float* x    = (const float*)d_in[0];
    const int*   eidx = (const int*)d_in[1];
    const float* ew   = (const float*)d_in[2];
    const int*   batch= (const int*)d_in[3];
    const float* W1 = (const float*)d_in[4];
    const float* b1 = (const float*)d_in[5];
    const float* W2 = (const float*)d_in[6];
    const float* b2 = (const float*)d_in[7];
    const float* W3 = (const float*)d_in[8];
    const float* b3 = (const float*)d_in[9];
    const float* Wout = (const float*)d_in[10];
    const float* bout = (const float*)d_in[11];
    float* out = (float*)d_out;

    float* A    = (float*)d_ws;            // N*32
    float* B    = A + (size_t)NN * HD;     // N*32
    float* dinv = B + (size_t)NN * HD;     // N
    float* nrm  = dinv + NN;               // E
    const int* row = eidx;        // sources
    const int* col = eidx + NE;   // targets

    k_deg_init<<<(NN + 255) / 256, 256, 0, stream>>>(dinv);
    k_deg_acc<<<(NE + 255) / 256, 256, 0, stream>>>(col, ew, dinv);
    k_dinv<<<(NN + 255) / 256, 256, 0, stream>>>(dinv);
    k_norm<<<(NE + 255) / 256, 256, 0, stream>>>(row, col, ew, dinv, nrm);

    const float* Ws[3] = {W1, W2, W3};
    const float* bs[3] = {nullptr, b1, b2};
    const float* cur = x;
    for (int l = 0; l < 3; ++l) {
        if (l == 0)
            k_gemm<false><<<NN / 8, 256, 0, stream>>>(cur, Ws[l], nullptr, B);
        else
            k_gemm<true><<<NN / 8, 256, 0, stream>>>(cur, Ws[l], bs[l], B);
        k_selfloop<<<NN * HD / 256, 256, 0, stream>>>(B, dinv, A);
        k_scatter<<<(NE * 8) / 256, 256, 0, stream>>>(row, col, nrm, B, A);
        cur = A;
    }
    k_pool_head<<<NG, 1024, 0, stream>>>(A, b3, batch, Wout, bout, out);
}

// Round 2
// 577.744 us; speedup vs baseline: 3.6976x; 3.6976x over previous
//
#include <hip/hip_runtime.h>
#include <math.h>

#define NN 100000
#define NE 1600000
#define HD 32
#define NG 64
#define NC 8
#define NB_SCAN 98  // ceil(NN/1024)

// ---------- graph normalization ----------
__global__ __launch_bounds__(256) void k_deg_init(float* deg) {
    int i = blockIdx.x * 256 + threadIdx.x;
    if (i < NN) deg[i] = 1.0f;  // self-loop weight
}

__global__ __launch_bounds__(256) void k_deg_acc(const int* __restrict__ col,
                                                 const float* __restrict__ w,
                                                 float* deg) {
    int e = blockIdx.x * 256 + threadIdx.x;
    if (e < NE) atomicAdd(&deg[col[e]], w[e]);
}

__global__ __launch_bounds__(256) void k_dinv(float* deg) {
    int i = blockIdx.x * 256 + threadIdx.x;
    if (i < NN) { float d = deg[i]; deg[i] = d > 0.0f ? rsqrtf(d) : 0.0f; }
}

// ---------- CSR build (by target col) ----------
__global__ __launch_bounds__(256) void k_zero(int* p, int n) {
    int i = blockIdx.x * 256 + threadIdx.x;
    if (i < n) p[i] = 0;
}

__global__ __launch_bounds__(256) void k_count(const int* __restrict__ col, int* cnt) {
    int e = blockIdx.x * 256 + threadIdx.x;
    if (e < NE) atomicAdd(&cnt[col[e]], 1);
}

__global__ __launch_bounds__(1024) void k_scan1(const int* __restrict__ cnt,
                                                int* __restrict__ off,
                                                int* __restrict__ bsum) {
    __shared__ int s[1024];
    int tid = threadIdx.x;
    int i = blockIdx.x * 1024 + tid;
    int v = (i < NN) ? cnt[i] : 0;
    s[tid] = v;
    __syncthreads();
#pragma unroll
    for (int d = 1; d < 1024; d <<= 1) {
        int t = (tid >= d) ? s[tid - d] : 0;
        __syncthreads();
        s[tid] += t;
        __syncthreads();
    }
    if (i < NN) off[i] = s[tid] - v;  // exclusive
    if (tid == 1023) bsum[blockIdx.x] = s[1023];
}

__global__ __launch_bounds__(128) void k_scan2(int* bsum) {
    __shared__ int s[128];
    int tid = threadIdx.x;
    int v = (tid < NB_SCAN) ? bsum[tid] : 0;
    s[tid] = v;
    __syncthreads();
#pragma unroll
    for (int d = 1; d < 128; d <<= 1) {
        int t = (tid >= d) ? s[tid - d] : 0;
        __syncthreads();
        s[tid] += t;
        __syncthreads();
    }
    if (tid < NB_SCAN) bsum[tid] = s[tid] - v;  // exclusive block offsets
}

__global__ __launch_bounds__(256) void k_scan3(int* __restrict__ off,
                                               const int* __restrict__ bsum,
                                               int* __restrict__ cursor) {
    int i = blockIdx.x * 256 + threadIdx.x;
    if (i < NN) {
        int o = off[i] + bsum[i >> 10];
        off[i] = o;
        cursor[i] = o;
    }
}

// fill sorted (row, norm) pairs; also computes norm on the fly
__global__ __launch_bounds__(256) void k_fill(const int* __restrict__ row,
                                              const int* __restrict__ col,
                                              const float* __restrict__ w,
                                              const float* __restrict__ dinv,
                                              int* __restrict__ cursor,
                                              float2* __restrict__ pairs) {
    int e = blockIdx.x * 256 + threadIdx.x;
    if (e >= NE) return;
    int r = row[e], c = col[e];
    float nm = dinv[r] * w[e] * dinv[c];
    int pos = atomicAdd(&cursor[c], 1);
    pairs[pos] = make_float2(__int_as_float(r), nm);
}

// ---------- feature transform: out = act(in) @ W ----------
template <bool PREACT>
__global__ __launch_bounds__(256) void k_gemm(const float* __restrict__ in,
                                              const float* __restrict__ Wm,
                                              const float* __restrict__ bprev,
                                              float* __restrict__ out) {
    __shared__ float sW[32 * 32];
    __shared__ float sX[8 * 32];
    int tid = threadIdx.x;
    int base = blockIdx.x * 8;
    ((float4*)sW)[tid] = ((const float4*)Wm)[tid];
    if (tid < 64) {
        float4 v = ((const float4*)(in + base * 32))[tid];
        if (PREACT) {
            int k4 = (tid & 7) * 4;
            v.x = fmaxf(v.x + bprev[k4 + 0], 0.0f);
            v.y = fmaxf(v.y + bprev[k4 + 1], 0.0f);
            v.z = fmaxf(v.z + bprev[k4 + 2], 0.0f);
            v.w = fmaxf(v.w + bprev[k4 + 3], 0.0f);
        }
        ((float4*)sX)[tid] = v;
    }
    __syncthreads();
    int c = tid & 31, nl = tid >> 5;
    float acc = 0.0f;
#pragma unroll
    for (int k = 0; k < 32; ++k) acc = fmaf(sX[nl * 32 + k], sW[k * 32 + c], acc);
    out[(base + nl) * 32 + c] = acc;
}

// ---------- gather aggregation: agg[n] = dinv[n]^2*h[n] + sum_e nrm*h[row] ----------
__global__ __launch_bounds__(256) void k_gather(const float* __restrict__ h,
                                                const int* __restrict__ off,
                                                const int* __restrict__ endo,
                                                const float* __restrict__ dinv,
                                                const float2* __restrict__ pairs,
                                                float* __restrict__ agg) {
    int t = blockIdx.x * 256 + threadIdx.x;  // over NN*32, exact multiple
    int n = t >> 5, c = t & 31;
    int start = off[n], end = endo[n];
    float di = dinv[n];
    float acc = di * di * h[t];  // self-loop
    for (int e = start; e < end; ++e) {
        float2 p = pairs[e];
        int r = __float_as_int(p.x);
        acc = fmaf(p.y, h[r * 32 + c], acc);
    }
    agg[t] = acc;
}

// ---------- global mean pool + linear head + log_softmax ----------
__global__ __launch_bounds__(1024) void k_pool_head(const float* __restrict__ agg3,
                                                    const float* __restrict__ b3,
                                                    const int* __restrict__ batch,
                                                    const float* __restrict__ Wout,
                                                    const float* __restrict__ bout,
                                                    float* __restrict__ out) {
    int g = blockIdx.x;
    __shared__ int sb[2];
    if (threadIdx.x == 0) {
        int lo = 0, hi = NN;
        while (lo < hi) { int m = (lo + hi) >> 1; if (batch[m] < g) lo = m + 1; else hi = m; }
        sb[0] = lo;
        lo = 0; hi = NN;
        while (lo < hi) { int m = (lo + hi) >> 1; if (batch[m] < g + 1) lo = m + 1; else hi = m; }
        sb[1] = lo;
    }
    __syncthreads();
    int start = sb[0], end = sb[1];
    int c = threadIdx.x & 31, grp = threadIdx.x >> 5;
    float bc = b3[c];
    float acc = 0.0f;
    for (int n = start + grp; n < end; n += 32)
        acc += fmaxf(agg3[n * 32 + c] + bc, 0.0f);
    __shared__ float red[32 * 32];
    red[grp * 32 + c] = acc;
    __syncthreads();
    __shared__ float pooled[32];
    if (threadIdx.x < 32) {
        float s = 0.0f;
#pragma unroll
        for (int gr = 0; gr < 32; ++gr) s += red[gr * 32 + threadIdx.x];
        pooled[threadIdx.x] = s / fmaxf((float)(end - start), 1.0f);
    }
    __syncthreads();
    __shared__ float slog[8];
    if (threadIdx.x < 8) {
        float l = bout[threadIdx.x];
#pragma unroll
        for (int k = 0; k < 32; ++k) l = fmaf(pooled[k], Wout[k * 8 + threadIdx.x], l);
        slog[threadIdx.x] = l;
    }
    __syncthreads();
    if (threadIdx.x < 8) {
        float m = slog[0];
#pragma unroll
        for (int i = 1; i < 8; ++i) m = fmaxf(m, slog[i]);
        float s = 0.0f;
#pragma unroll
        for (int i = 0; i < 8; ++i) s += expf(slog[i] - m);
        out[g * NC + threadIdx.x] = slog[threadIdx.x] - m - logf(s);
    }
}

extern "C" void kernel_launch(void* const* d_in, const int* in_sizes, int n_in,
                              void* d_out, int out_size, void* d_ws, size_t ws_size,
                              hipStream_t stream) {
    const float* x     = (const float*)d_in[0];
    const int*   eidx  = (const int*)d_in[1];
    const float* ew    = (const float*)d_in[2];
    const int*   batch = (const int*)d_in[3];
    const float* W1 = (const float*)d_in[4];
    const float* b1 = (const float*)d_in[5];
    const float* W2 = (const float*)d_in[6];
    const float* b2 = (const float*)d_in[7];
    const float* W3 = (const float*)d_in[8];
    const float* b3 = (const float*)d_in[9];
    const float* Wout = (const float*)d_in[10];
    const float* bout = (const float*)d_in[11];
    float* out = (float*)d_out;

    // workspace layout (~39.6 MB)
    float*  A      = (float*)d_ws;                 // NN*32
    float*  B      = A + (size_t)NN * HD;          // NN*32
    float2* pairs  = (float2*)(B + (size_t)NN * HD);  // NE
    float*  dinv   = (float*)(pairs + NE);         // NN
    int*    off    = (int*)(dinv + NN);            // NN
    int*    cursor = off + NN;                     // NN
    int*    cnt    = (int*)B;                      // alias: B unused until layer 0 GEMM
    int*    bsum   = cnt + NN;                     // NB_SCAN, still inside B

    const int* row = eidx;        // sources
    const int* col = eidx + NE;   // targets

    // degree + dinv
    k_deg_init<<<(NN + 255) / 256, 256, 0, stream>>>(dinv);
    k_deg_acc<<<(NE + 255) / 256, 256, 0, stream>>>(col, ew, dinv);
    k_dinv<<<(NN + 255) / 256, 256, 0, stream>>>(dinv);

    // CSR build
    k_zero<<<(NN + 255) / 256, 256, 0, stream>>>(cnt, NN);
    k_count<<<(NE + 255) / 256, 256, 0, stream>>>(col, cnt);
    k_scan1<<<NB_SCAN, 1024, 0, stream>>>(cnt, off, bsum);
    k_scan2<<<1, 128, 0, stream>>>(bsum);
    k_scan3<<<(NN + 255) / 256, 256, 0, stream>>>(off, bsum, cursor);
    k_fill<<<(NE + 255) / 256, 256, 0, stream>>>(row, col, ew, dinv, cursor, pairs);
    // post-fill: cursor[n] == end offset of node n

    const float* Ws[3] = {W1, W2, W3};
    const float* bs[3] = {nullptr, b1, b2};
    const float* cur = x;
    for (int l = 0; l < 3; ++l) {
        if (l == 0)
            k_gemm<false><<<NN / 8, 256, 0, stream>>>(cur, Ws[l], nullptr, B);
        else
            k_gemm<true><<<NN / 8, 256, 0, stream>>>(cur, Ws[l], bs[l], B);
        k_gather<<<NN * HD / 256, 256, 0, stream>>>(B, off, cursor, dinv, pairs, A);
        cur = A;
    }
    k_pool_head<<<NG, 1024, 0, stream>>>(A, b3, batch, Wout, bout, out);
}

// Round 3
// 406.886 us; speedup vs baseline: 5.2503x; 1.4199x over previous
//
#include <hip/hip_runtime.h>
#include <math.h>

#define NN 100000
#define NE 1600000
#define HD 32
#define NG 64
#define NC 8
#define NB_SCAN 98  // ceil(NN/1024)

// ---------- init: deg=1 (self-loop), cnt=0 ----------
__global__ __launch_bounds__(256) void k_init(float* deg, int* cnt) {
    int i = blockIdx.x * 256 + threadIdx.x;
    if (i < NN) { deg[i] = 1.0f; cnt[i] = 0; }
}

// ---------- single edge pass: weighted degree + CSR count ----------
__global__ __launch_bounds__(256) void k_edge_pass(const int* __restrict__ col,
                                                   const float* __restrict__ w,
                                                   float* deg, int* cnt) {
    int e = blockIdx.x * 256 + threadIdx.x;
    if (e < NE) {
        int c = col[e];
        atomicAdd(&deg[c], w[e]);
        atomicAdd(&cnt[c], 1);
    }
}

// ---------- scan for CSR offsets ----------
__global__ __launch_bounds__(1024) void k_scan1(const int* __restrict__ cnt,
                                                int* __restrict__ off,
                                                int* __restrict__ bsum) {
    __shared__ int s[1024];
    int tid = threadIdx.x;
    int i = blockIdx.x * 1024 + tid;
    int v = (i < NN) ? cnt[i] : 0;
    s[tid] = v;
    __syncthreads();
#pragma unroll
    for (int d = 1; d < 1024; d <<= 1) {
        int t = (tid >= d) ? s[tid - d] : 0;
        __syncthreads();
        s[tid] += t;
        __syncthreads();
    }
    if (i < NN) off[i] = s[tid] - v;  // exclusive
    if (tid == 1023) bsum[blockIdx.x] = s[1023];
}

__global__ __launch_bounds__(128) void k_scan2(int* bsum) {
    __shared__ int s[128];
    int tid = threadIdx.x;
    int v = (tid < NB_SCAN) ? bsum[tid] : 0;
    s[tid] = v;
    __syncthreads();
#pragma unroll
    for (int d = 1; d < 128; d <<= 1) {
        int t = (tid >= d) ? s[tid - d] : 0;
        __syncthreads();
        s[tid] += t;
        __syncthreads();
    }
    if (tid < NB_SCAN) bsum[tid] = s[tid] - v;  // exclusive block offsets
}

// finalize offsets, init cursor, and compute dinv = rsqrt(deg) in place
__global__ __launch_bounds__(256) void k_scan3(int* __restrict__ off,
                                               const int* __restrict__ bsum,
                                               int* __restrict__ cursor,
                                               float* __restrict__ deg) {
    int i = blockIdx.x * 256 + threadIdx.x;
    if (i < NN) {
        int o = off[i] + bsum[i >> 10];
        off[i] = o;
        cursor[i] = o;
        float d = deg[i];
        deg[i] = d > 0.0f ? rsqrtf(d) : 0.0f;
    }
}

// fill sorted (row, norm) pairs
__global__ __launch_bounds__(256) void k_fill(const int* __restrict__ row,
                                              const int* __restrict__ col,
                                              const float* __restrict__ w,
                                              const float* __restrict__ dinv,
                                              int* __restrict__ cursor,
                                              float2* __restrict__ pairs) {
    int e = blockIdx.x * 256 + threadIdx.x;
    if (e >= NE) return;
    int r = row[e], c = col[e];
    float nm = dinv[r] * w[e] * dinv[c];
    int pos = atomicAdd(&cursor[c], 1);
    pairs[pos] = make_float2(__int_as_float(r), nm);
}

// ---------- feature transform: out = act(in) @ W ----------
template <bool PREACT>
__global__ __launch_bounds__(256) void k_gemm(const float* __restrict__ in,
                                              const float* __restrict__ Wm,
                                              const float* __restrict__ bprev,
                                              float* __restrict__ out) {
    __shared__ float sW[32 * 32];
    __shared__ float sX[8 * 32];
    int tid = threadIdx.x;
    int base = blockIdx.x * 8;
    ((float4*)sW)[tid] = ((const float4*)Wm)[tid];
    if (tid < 64) {
        float4 v = ((const float4*)(in + base * 32))[tid];
        if (PREACT) {
            int k4 = (tid & 7) * 4;
            v.x = fmaxf(v.x + bprev[k4 + 0], 0.0f);
            v.y = fmaxf(v.y + bprev[k4 + 1], 0.0f);
            v.z = fmaxf(v.z + bprev[k4 + 2], 0.0f);
            v.w = fmaxf(v.w + bprev[k4 + 3], 0.0f);
        }
        ((float4*)sX)[tid] = v;
    }
    __syncthreads();
    int c = tid & 31, nl = tid >> 5;
    float acc = 0.0f;
#pragma unroll
    for (int k = 0; k < 32; ++k) acc = fmaf(sX[nl * 32 + k], sW[k * 32 + c], acc);
    out[(base + nl) * 32 + c] = acc;
}

// ---------- gather aggregation, software-pipelined ----------
__global__ __launch_bounds__(256) void k_gather(const float* __restrict__ h,
                                                const int* __restrict__ off,
                                                const int* __restrict__ endo,
                                                const float* __restrict__ dinv,
                                                const float2* __restrict__ pairs,
                                                float* __restrict__ agg) {
    int t = blockIdx.x * 256 + threadIdx.x;  // over NN*32
    int n = t >> 5, c = t & 31;
    int start = off[n], end = endo[n];
    float di = dinv[n];
    float acc = di * di * h[t];  // self-loop
    int e = start;
    // 8-deep: batch pair loads, then 8 independent h loads in flight
    for (; e + 8 <= end; e += 8) {
        float2 p[8];
#pragma unroll
        for (int k = 0; k < 8; ++k) p[k] = pairs[e + k];
        float v[8];
#pragma unroll
        for (int k = 0; k < 8; ++k) v[k] = h[__float_as_int(p[k].x) * 32 + c];
#pragma unroll
        for (int k = 0; k < 8; ++k) acc = fmaf(p[k].y, v[k], acc);
    }
    // 4-deep
    for (; e + 4 <= end; e += 4) {
        float2 p[4];
#pragma unroll
        for (int k = 0; k < 4; ++k) p[k] = pairs[e + k];
        float v[4];
#pragma unroll
        for (int k = 0; k < 4; ++k) v[k] = h[__float_as_int(p[k].x) * 32 + c];
#pragma unroll
        for (int k = 0; k < 4; ++k) acc = fmaf(p[k].y, v[k], acc);
    }
    for (; e < end; ++e) {
        float2 p = pairs[e];
        acc = fmaf(p.y, h[__float_as_int(p.x) * 32 + c], acc);
    }
    agg[t] = acc;
}

// ---------- global mean pool + linear head + log_softmax ----------
__global__ __launch_bounds__(1024) void k_pool_head(const float* __restrict__ agg3,
                                                    const float* __restrict__ b3,
                                                    const int* __restrict__ batch,
                                                    const float* __restrict__ Wout,
                                                    const float* __restrict__ bout,
                                                    float* __restrict__ out) {
    int g = blockIdx.x;
    __shared__ int sb[2];
    if (threadIdx.x == 0) {
        int lo = 0, hi = NN;
        while (lo < hi) { int m = (lo + hi) >> 1; if (batch[m] < g) lo = m + 1; else hi = m; }
        sb[0] = lo;
        lo = 0; hi = NN;
        while (lo < hi) { int m = (lo + hi) >> 1; if (batch[m] < g + 1) lo = m + 1; else hi = m; }
        sb[1] = lo;
    }
    __syncthreads();
    int start = sb[0], end = sb[1];
    int c = threadIdx.x & 31, grp = threadIdx.x >> 5;
    float bc = b3[c];
    float acc = 0.0f;
    for (int n = start + grp; n < end; n += 32)
        acc += fmaxf(agg3[n * 32 + c] + bc, 0.0f);
    __shared__ float red[32 * 32];
    red[grp * 32 + c] = acc;
    __syncthreads();
    __shared__ float pooled[32];
    if (threadIdx.x < 32) {
        float s = 0.0f;
#pragma unroll
        for (int gr = 0; gr < 32; ++gr) s += red[gr * 32 + threadIdx.x];
        pooled[threadIdx.x] = s / fmaxf((float)(end - start), 1.0f);
    }
    __syncthreads();
    __shared__ float slog[8];
    if (threadIdx.x < 8) {
        float l = bout[threadIdx.x];
#pragma unroll
        for (int k = 0; k < 32; ++k) l = fmaf(pooled[k], Wout[k * 8 + threadIdx.x], l);
        slog[threadIdx.x] = l;
    }
    __syncthreads();
    if (threadIdx.x < 8) {
        float m = slog[0];
#pragma unroll
        for (int i = 1; i < 8; ++i) m = fmaxf(m, slog[i]);
        float s = 0.0f;
#pragma unroll
        for (int i = 0; i < 8; ++i) s += expf(slog[i] - m);
        out[g * NC + threadIdx.x] = slog[threadIdx.x] - m - logf(s);
    }
}

extern "C" void kernel_launch(void* const* d_in, const int* in_sizes, int n_in,
                              void* d_out, int out_size, void* d_ws, size_t ws_size,
                              hipStream_t stream) {
    const float* x     = (const float*)d_in[0];
    const int*   eidx  = (const int*)d_in[1];
    const float* ew    = (const float*)d_in[2];
    const int*   batch = (const int*)d_in[3];
    const float* W1 = (const float*)d_in[4];
    const float* b1 = (const float*)d_in[5];
    const float* W2 = (const float*)d_in[6];
    const float* b2 = (const float*)d_in[7];
    const float* W3 = (const float*)d_in[8];
    const float* b3 = (const float*)d_in[9];
    const float* Wout = (const float*)d_in[10];
    const float* bout = (const float*)d_in[11];
    float* out = (float*)d_out;

    // workspace layout
    float*  A      = (float*)d_ws;                    // NN*32
    float*  B      = A + (size_t)NN * HD;             // NN*32
    float2* pairs  = (float2*)(B + (size_t)NN * HD);  // NE
    float*  dinv   = (float*)(pairs + NE);            // NN (deg -> dinv in place)
    int*    off    = (int*)(dinv + NN);               // NN
    int*    cursor = off + NN;                        // NN
    int*    cnt    = (int*)B;                         // alias: B unused until layer-0 GEMM
    int*    bsum   = cnt + NN;                        // NB_SCAN, inside B

    const int* row = eidx;        // sources
    const int* col = eidx + NE;   // targets

    k_init<<<(NN + 255) / 256, 256, 0, stream>>>(dinv, cnt);
    k_edge_pass<<<(NE + 255) / 256, 256, 0, stream>>>(col, ew, dinv, cnt);
    k_scan1<<<NB_SCAN, 1024, 0, stream>>>(cnt, off, bsum);
    k_scan2<<<1, 128, 0, stream>>>(bsum);
    k_scan3<<<(NN + 255) / 256, 256, 0, stream>>>(off, bsum, cursor, dinv);
    k_fill<<<(NE + 255) / 256, 256, 0, stream>>>(row, col, ew, dinv, cursor, pairs);
    // post-fill: cursor[n] == end offset of node n

    const float* Ws[3] = {W1, W2, W3};
    const float* bs[3] = {nullptr, b1, b2};
    const float* cur = x;
    for (int l = 0; l < 3; ++l) {
        if (l == 0)
            k_gemm<false><<<NN / 8, 256, 0, stream>>>(cur, Ws[l], nullptr, B);
        else
            k_gemm<true><<<NN / 8, 256, 0, stream>>>(cur, Ws[l], bs[l], B);
        k_gather<<<NN * HD / 256, 256, 0, stream>>>(B, off, cursor, dinv, pairs, A);
        cur = A;
    }
    k_pool_head<<<NG, 1024, 0, stream>>>(A, b3, batch, Wout, bout, out);
}

// Round 4
// 306.702 us; speedup vs baseline: 6.9653x; 1.3266x over previous
//
#include <hip/hip_runtime.h>
#include <math.h>

#define NN 100000
#define NE 1600000
#define HD 32
#define NG 64
#define NC 8
#define CAP 64      // bucket capacity; P(Poisson(16) >= 64) ~ 1e-18
#define NB_SCAN 98  // ceil(NN/1024)

// ---------- zero int array ----------
__global__ __launch_bounds__(256) void k_zero(int* p, int n) {
    int i = blockIdx.x * 256 + threadIdx.x;
    if (i < n) p[i] = 0;
}

// ---------- BUCKET path: single edge pass, direct scatter ----------
__global__ __launch_bounds__(256) void k_fill_direct(const int* __restrict__ row,
                                                     const int* __restrict__ col,
                                                     const float* __restrict__ w,
                                                     int* __restrict__ cnt,
                                                     float2* __restrict__ pairs) {
    int e = blockIdx.x * 256 + threadIdx.x;
    if (e >= NE) return;
    int r = row[e], c = col[e];
    int pos = atomicAdd(&cnt[c], 1);
    pairs[(size_t)c * CAP + pos] = make_float2(__int_as_float(r), w[e]);
}

// ---------- CSR path: count ----------
__global__ __launch_bounds__(256) void k_count(const int* __restrict__ col, int* cnt) {
    int e = blockIdx.x * 256 + threadIdx.x;
    if (e < NE) atomicAdd(&cnt[col[e]], 1);
}

__global__ __launch_bounds__(1024) void k_scan1(const int* __restrict__ cnt,
                                                int* __restrict__ off,
                                                int* __restrict__ bsum) {
    __shared__ int s[1024];
    int tid = threadIdx.x;
    int i = blockIdx.x * 1024 + tid;
    int v = (i < NN) ? cnt[i] : 0;
    s[tid] = v;
    __syncthreads();
#pragma unroll
    for (int d = 1; d < 1024; d <<= 1) {
        int t = (tid >= d) ? s[tid - d] : 0;
        __syncthreads();
        s[tid] += t;
        __syncthreads();
    }
    if (i < NN) off[i] = s[tid] - v;  // exclusive
    if (tid == 1023) bsum[blockIdx.x] = s[1023];
}

__global__ __launch_bounds__(128) void k_scan2(int* bsum) {
    __shared__ int s[128];
    int tid = threadIdx.x;
    int v = (tid < NB_SCAN) ? bsum[tid] : 0;
    s[tid] = v;
    __syncthreads();
#pragma unroll
    for (int d = 1; d < 128; d <<= 1) {
        int t = (tid >= d) ? s[tid - d] : 0;
        __syncthreads();
        s[tid] += t;
        __syncthreads();
    }
    if (tid < NB_SCAN) bsum[tid] = s[tid] - v;
}

__global__ __launch_bounds__(256) void k_scan3(int* __restrict__ off,
                                               const int* __restrict__ bsum,
                                               int* __restrict__ cursor) {
    int i = blockIdx.x * 256 + threadIdx.x;
    if (i < NN) {
        int o = off[i] + bsum[i >> 10];
        off[i] = o;
        cursor[i] = o;
    }
}

__global__ __launch_bounds__(256) void k_fill_csr(const int* __restrict__ row,
                                                  const int* __restrict__ col,
                                                  const float* __restrict__ w,
                                                  int* __restrict__ cursor,
                                                  float2* __restrict__ pairs) {
    int e = blockIdx.x * 256 + threadIdx.x;
    if (e >= NE) return;
    int r = row[e], c = col[e];
    int pos = atomicAdd(&cursor[c], 1);
    pairs[pos] = make_float2(__int_as_float(r), w[e]);
}

// ---------- per-node range helpers ----------
// BUCKET: start = n*CAP, len = a[n].   CSR: start = a[n], len = b[n]-a[n].

// deg[n] = 1 + sum w  ->  dinv[n] = rsqrt(deg)
template <bool BUCKET>
__global__ __launch_bounds__(256) void k_node_dinv(const int* __restrict__ a,
                                                   const int* __restrict__ b,
                                                   const float2* __restrict__ pairs,
                                                   float* __restrict__ dinv) {
    int n = blockIdx.x * 256 + threadIdx.x;
    if (n >= NN) return;
    size_t start = BUCKET ? (size_t)n * CAP : (size_t)a[n];
    int cn = BUCKET ? a[n] : (b[n] - a[n]);
    float s = 1.0f;  // self-loop weight
    for (int k = 0; k < cn; ++k) s += pairs[start + k].y;
    dinv[n] = rsqrtf(s);
}

// pairs.y <- dinv[row] * w * dinv[col]
template <bool BUCKET>
__global__ __launch_bounds__(256) void k_normalize(const int* __restrict__ a,
                                                   const int* __restrict__ b,
                                                   const float* __restrict__ dinv,
                                                   float2* __restrict__ pairs) {
    int t = blockIdx.x * 256 + threadIdx.x;  // NN*8
    int n = t >> 3, q = t & 7;
    size_t start = BUCKET ? (size_t)n * CAP : (size_t)a[n];
    int cn = BUCKET ? a[n] : (b[n] - a[n]);
    float dn = dinv[n];
    for (int k = q; k < cn; k += 8) {
        float2 p = pairs[start + k];
        p.y = dinv[__float_as_int(p.x)] * p.y * dn;
        pairs[start + k] = p;
    }
}

// ---------- feature transform: out = act(in) @ W ----------
template <bool PREACT>
__global__ __launch_bounds__(256) void k_gemm(const float* __restrict__ in,
                                              const float* __restrict__ Wm,
                                              const float* __restrict__ bprev,
                                              float* __restrict__ out) {
    __shared__ float sW[32 * 32];
    __shared__ float sX[8 * 32];
    int tid = threadIdx.x;
    int base = blockIdx.x * 8;
    ((float4*)sW)[tid] = ((const float4*)Wm)[tid];
    if (tid < 64) {
        float4 v = ((const float4*)(in + base * 32))[tid];
        if (PREACT) {
            int k4 = (tid & 7) * 4;
            v.x = fmaxf(v.x + bprev[k4 + 0], 0.0f);
            v.y = fmaxf(v.y + bprev[k4 + 1], 0.0f);
            v.z = fmaxf(v.z + bprev[k4 + 2], 0.0f);
            v.w = fmaxf(v.w + bprev[k4 + 3], 0.0f);
        }
        ((float4*)sX)[tid] = v;
    }
    __syncthreads();
    int c = tid & 31, nl = tid >> 5;
    float acc = 0.0f;
#pragma unroll
    for (int k = 0; k < 32; ++k) acc = fmaf(sX[nl * 32 + k], sW[k * 32 + c], acc);
    out[(base + nl) * 32 + c] = acc;
}

// ---------- gather aggregation, float4-per-thread, software-pipelined ----------
template <bool BUCKET>
__global__ __launch_bounds__(256) void k_gather4(const float4* __restrict__ h4,
                                                 const int* __restrict__ a,
                                                 const int* __restrict__ b,
                                                 const float* __restrict__ dinv,
                                                 const float2* __restrict__ pairs,
                                                 float4* __restrict__ agg4) {
    int t = blockIdx.x * 256 + threadIdx.x;  // NN*8 exactly
    int n = t >> 3, c4 = t & 7;
    size_t start = BUCKET ? (size_t)n * CAP : (size_t)a[n];
    int cn = BUCKET ? a[n] : (b[n] - a[n]);
    float di = dinv[n];
    float sl = di * di;
    float4 hv = h4[(size_t)n * 8 + c4];
    float4 acc = make_float4(sl * hv.x, sl * hv.y, sl * hv.z, sl * hv.w);
    const float2* pp = pairs + start;
    int k = 0;
    for (; k + 8 <= cn; k += 8) {
        float2 p[8];
#pragma unroll
        for (int j = 0; j < 8; ++j) p[j] = pp[k + j];
        float4 v[8];
#pragma unroll
        for (int j = 0; j < 8; ++j) v[j] = h4[(size_t)__float_as_int(p[j].x) * 8 + c4];
#pragma unroll
        for (int j = 0; j < 8; ++j) {
            acc.x = fmaf(p[j].y, v[j].x, acc.x);
            acc.y = fmaf(p[j].y, v[j].y, acc.y);
            acc.z = fmaf(p[j].y, v[j].z, acc.z);
            acc.w = fmaf(p[j].y, v[j].w, acc.w);
        }
    }
    for (; k + 4 <= cn; k += 4) {
        float2 p[4];
#pragma unroll
        for (int j = 0; j < 4; ++j) p[j] = pp[k + j];
        float4 v[4];
#pragma unroll
        for (int j = 0; j < 4; ++j) v[j] = h4[(size_t)__float_as_int(p[j].x) * 8 + c4];
#pragma unroll
        for (int j = 0; j < 4; ++j) {
            acc.x = fmaf(p[j].y, v[j].x, acc.x);
            acc.y = fmaf(p[j].y, v[j].y, acc.y);
            acc.z = fmaf(p[j].y, v[j].z, acc.z);
            acc.w = fmaf(p[j].y, v[j].w, acc.w);
        }
    }
    for (; k < cn; ++k) {
        float2 p = pp[k];
        float4 v = h4[(size_t)__float_as_int(p.x) * 8 + c4];
        acc.x = fmaf(p.y, v.x, acc.x);
        acc.y = fmaf(p.y, v.y, acc.y);
        acc.z = fmaf(p.y, v.z, acc.z);
        acc.w = fmaf(p.y, v.w, acc.w);
    }
    agg4[t] = acc;
}

// ---------- global mean pool + linear head + log_softmax ----------
__global__ __launch_bounds__(1024) void k_pool_head(const float* __restrict__ agg3,
                                                    const float* __restrict__ b3,
                                                    const int* __restrict__ batch,
                                                    const float* __restrict__ Wout,
                                                    const float* __restrict__ bout,
                                                    float* __restrict__ out) {
    int g = blockIdx.x;
    __shared__ int sb[2];
    if (threadIdx.x == 0) {
        int lo = 0, hi = NN;
        while (lo < hi) { int m = (lo + hi) >> 1; if (batch[m] < g) lo = m + 1; else hi = m; }
        sb[0] = lo;
        lo = 0; hi = NN;
        while (lo < hi) { int m = (lo + hi) >> 1; if (batch[m] < g + 1) lo = m + 1; else hi = m; }
        sb[1] = lo;
    }
    __syncthreads();
    int start = sb[0], end = sb[1];
    int c = threadIdx.x & 31, grp = threadIdx.x >> 5;
    float bc = b3[c];
    float acc = 0.0f;
    for (int n = start + grp; n < end; n += 32)
        acc += fmaxf(agg3[n * 32 + c] + bc, 0.0f);
    __shared__ float red[32 * 32];
    red[grp * 32 + c] = acc;
    __syncthreads();
    __shared__ float pooled[32];
    if (threadIdx.x < 32) {
        float s = 0.0f;
#pragma unroll
        for (int gr = 0; gr < 32; ++gr) s += red[gr * 32 + threadIdx.x];
        pooled[threadIdx.x] = s / fmaxf((float)(end - start), 1.0f);
    }
    __syncthreads();
    __shared__ float slog[8];
    if (threadIdx.x < 8) {
        float l = bout[threadIdx.x];
#pragma unroll
        for (int k = 0; k < 32; ++k) l = fmaf(pooled[k], Wout[k * 8 + threadIdx.x], l);
        slog[threadIdx.x] = l;
    }
    __syncthreads();
    if (threadIdx.x < 8) {
        float m = slog[0];
#pragma unroll
        for (int i = 1; i < 8; ++i) m = fmaxf(m, slog[i]);
        float s = 0.0f;
#pragma unroll
        for (int i = 0; i < 8; ++i) s += expf(slog[i] - m);
        out[g * NC + threadIdx.x] = slog[threadIdx.x] - m - logf(s);
    }
}

extern "C" void kernel_launch(void* const* d_in, const int* in_sizes, int n_in,
                              void* d_out, int out_size, void* d_ws, size_t ws_size,
                              hipStream_t stream) {
    const float* x     = (const float*)d_in[0];
    const int*   eidx  = (const int*)d_in[1];
    const float* ew    = (const float*)d_in[2];
    const int*   batch = (const int*)d_in[3];
    const float* W1 = (const float*)d_in[4];
    const float* b1 = (const float*)d_in[5];
    const float* W2 = (const float*)d_in[6];
    const float* b2 = (const float*)d_in[7];
    const float* W3 = (const float*)d_in[8];
    const float* b3 = (const float*)d_in[9];
    const float* Wout = (const float*)d_in[10];
    const float* bout = (const float*)d_in[11];
    float* out = (float*)d_out;

    const int* row = eidx;        // sources
    const int* col = eidx + NE;   // targets

    // common layout: A, B, pairs, then small arrays
    float*  A     = (float*)d_ws;                    // NN*32 f
    float*  B     = A + (size_t)NN * HD;             // NN*32 f
    float2* pairs = (float2*)(B + (size_t)NN * HD);  // bucket: NN*CAP, csr: NE

    const size_t bucket_need = (size_t)NN * HD * 4 * 2            // A+B
                             + (size_t)NN * CAP * sizeof(float2)  // pairs
                             + (size_t)NN * 4 * 2;                // dinv+cnt
    bool bucket = ws_size >= bucket_need;

    const float* Ws[3] = {W1, W2, W3};
    const float* bs[3] = {nullptr, b1, b2};

    if (bucket) {
        float* dinv = (float*)(pairs + (size_t)NN * CAP);  // NN
        int*   cnt  = (int*)(dinv + NN);                   // NN

        k_zero<<<(NN + 255) / 256, 256, 0, stream>>>(cnt, NN);
        k_fill_direct<<<(NE + 255) / 256, 256, 0, stream>>>(row, col, ew, cnt, pairs);
        k_node_dinv<true><<<(NN + 255) / 256, 256, 0, stream>>>(cnt, nullptr, pairs, dinv);
        k_normalize<true><<<NN * 8 / 256, 256, 0, stream>>>(cnt, nullptr, dinv, pairs);

        const float* cur = x;
        for (int l = 0; l < 3; ++l) {
            if (l == 0)
                k_gemm<false><<<NN / 8, 256, 0, stream>>>(cur, Ws[l], nullptr, B);
            else
                k_gemm<true><<<NN / 8, 256, 0, stream>>>(cur, Ws[l], bs[l], B);
            k_gather4<true><<<NN * 8 / 256, 256, 0, stream>>>(
                (const float4*)B, cnt, nullptr, dinv, pairs, (float4*)A);
            cur = A;
        }
    } else {
        // exact-CSR fallback (proven ~40 MB footprint)
        float* dinv   = (float*)(pairs + NE);  // NN
        int*   off    = (int*)(dinv + NN);     // NN
        int*   cursor = off + NN;              // NN
        int*   cnt    = (int*)B;               // alias: B unused until layer-0 GEMM
        int*   bsum   = cnt + NN;              // NB_SCAN, inside B

        k_zero<<<(NN + 255) / 256, 256, 0, stream>>>(cnt, NN);
        k_count<<<(NE + 255) / 256, 256, 0, stream>>>(col, cnt);
        k_scan1<<<NB_SCAN, 1024, 0, stream>>>(cnt, off, bsum);
        k_scan2<<<1, 128, 0, stream>>>(bsum);
        k_scan3<<<(NN + 255) / 256, 256, 0, stream>>>(off, bsum, cursor);
        k_fill_csr<<<(NE + 255) / 256, 256, 0, stream>>>(row, col, ew, cursor, pairs);
        k_node_dinv<false><<<(NN + 255) / 256, 256, 0, stream>>>(off, cursor, pairs, dinv);
        k_normalize<false><<<NN * 8 / 256, 256, 0, stream>>>(off, cursor, dinv, pairs);

        const float* cur = x;
        for (int l = 0; l < 3; ++l) {
            if (l == 0)
                k_gemm<false><<<NN / 8, 256, 0, stream>>>(cur, Ws[l], nullptr, B);
            else
                k_gemm<true><<<NN / 8, 256, 0, stream>>>(cur, Ws[l], bs[l], B);
            k_gather4<false><<<NN * 8 / 256, 256, 0, stream>>>(
                (const float4*)B, off, cursor, dinv, pairs, (float4*)A);
            cur = A;
        }
    }
    k_pool_head<<<NG, 1024, 0, stream>>>(A, b3, batch, Wout, bout, out);
}

// Round 5
// 258.994 us; speedup vs baseline: 8.2483x; 1.1842x over previous
//
#include <hip/hip_runtime.h>
#include <math.h>

#define NN 100000
#define NE 1600000
#define HD 32
#define NG 64
#define NC 8
#define NORM_BLOCKS (NN * 8 / 256)   // 3125
#define GEMM0_BLOCKS (NN / 8)        // 12500

__device__ __forceinline__ float bf2f(unsigned short u) {
    return __uint_as_float(((unsigned int)u) << 16);
}
__device__ __forceinline__ unsigned short f2bf(float f) {
    unsigned int b = __float_as_uint(f);
    b = (b + 0x7FFFu + ((b >> 16) & 1u)) >> 16;  // RNE
    return (unsigned short)b;
}

// ---------- bucket fill: one pass, one atomic per edge ----------
__global__ __launch_bounds__(256) void k_fill(const int* __restrict__ row,
                                              const int* __restrict__ col,
                                              const float* __restrict__ w,
                                              int* __restrict__ cnt,
                                              float2* __restrict__ pairs, int cap) {
    int e = blockIdx.x * 256 + threadIdx.x;
    if (e >= NE) return;
    int r = __builtin_nontemporal_load(row + e);
    int c = __builtin_nontemporal_load(col + e);
    float ww = __builtin_nontemporal_load(w + e);
    int pos = atomicAdd(&cnt[c], 1);
    unsigned long long pv =
        ((unsigned long long)__float_as_uint(ww) << 32) | (unsigned int)r;
    __builtin_nontemporal_store(pv, (unsigned long long*)&pairs[(size_t)c * cap + pos]);
}

// ---------- dinv[n] = rsqrt(1 + sum w), 8 lanes per node ----------
__global__ __launch_bounds__(256) void k_node_dinv(const int* __restrict__ cnt,
                                                   const float2* __restrict__ pairs,
                                                   float* __restrict__ dinv, int cap) {
    int t = blockIdx.x * 256 + threadIdx.x;  // NN*8 exact
    int n = t >> 3, q = t & 7;
    int cn = cnt[n];
    const float2* pp = pairs + (size_t)n * cap;
    float s = 0.0f;
    for (int k = q; k < cn; k += 8) s += pp[k].y;
    s += __shfl_xor(s, 4);
    s += __shfl_xor(s, 2);
    s += __shfl_xor(s, 1);
    if (q == 0) dinv[n] = rsqrtf(1.0f + s);
}

// ---------- heterogeneous: normalize pairs  ||  h1 = x @ W1 (bf16 out) ----------
__global__ __launch_bounds__(256) void k_norm_gemm0(const int* __restrict__ cnt,
                                                    const float* __restrict__ dinv,
                                                    float2* __restrict__ pairs, int cap,
                                                    const float* __restrict__ x,
                                                    const float* __restrict__ W1,
                                                    unsigned short* __restrict__ h1) {
    __shared__ float sW[32 * 32];
    __shared__ float sX[8 * 32];
    int tid = threadIdx.x;
    if (blockIdx.x < NORM_BLOCKS) {
        int t = blockIdx.x * 256 + tid;
        int n = t >> 3, q = t & 7;
        int cn = cnt[n];
        float dn = dinv[n];
        float2* pp = pairs + (size_t)n * cap;
        for (int k = q; k < cn; k += 8) {
            float2 p = pp[k];
            p.y = dinv[__float_as_int(p.x)] * p.y * dn;
            pp[k] = p;
        }
    } else {
        int base = (blockIdx.x - NORM_BLOCKS) * 8;
        ((float4*)sW)[tid] = ((const float4*)W1)[tid];
        if (tid < 64) ((float4*)sX)[tid] = ((const float4*)(x + (size_t)base * 32))[tid];
        __syncthreads();
        int c = tid & 31, nl = tid >> 5;
        float acc = 0.0f;
#pragma unroll
        for (int k = 0; k < 32; ++k) acc = fmaf(sX[nl * 32 + k], sW[k * 32 + c], acc);
        h1[(size_t)(base + nl) * 32 + c] = f2bf(acc);
    }
}

// ---------- gather (bf16 h), optionally fused with next GEMM ----------
// g = dinv^2 * h[n] + sum nrm*h[r]  (fp32 acc)
// FUSE: hout = bf16( relu(g + bias) @ Wn )     else: aggout = g (fp32)
template <bool FUSE>
__global__ __launch_bounds__(256) void k_gather(const unsigned short* __restrict__ hb,
                                                const int* __restrict__ cnt,
                                                const float* __restrict__ dinv,
                                                const float2* __restrict__ pairs, int cap,
                                                const float* __restrict__ bias,
                                                const float* __restrict__ Wn,
                                                unsigned short* __restrict__ hout,
                                                float4* __restrict__ aggout) {
    __shared__ float sW[32 * 32];
    __shared__ float srow[32 * 33];
    int tid = threadIdx.x;
    if (FUSE) ((float4*)sW)[tid] = ((const float4*)Wn)[tid];
    int t = blockIdx.x * 256 + tid;  // NN*8 exact
    int n = t >> 3, c4 = t & 7;
    int cn = cnt[n];
    const float2* pp = pairs + (size_t)n * cap;
    float di = dinv[n];
    float sl = di * di;
    ushort4 hu = *((const ushort4*)(hb + (size_t)n * 32) + c4);
    float4 acc = make_float4(sl * bf2f(hu.x), sl * bf2f(hu.y),
                             sl * bf2f(hu.z), sl * bf2f(hu.w));
    int k = 0;
    for (; k + 8 <= cn; k += 8) {
        float2 p[8];
#pragma unroll
        for (int j = 0; j < 8; ++j) p[j] = pp[k + j];
        ushort4 v[8];
#pragma unroll
        for (int j = 0; j < 8; ++j)
            v[j] = *((const ushort4*)(hb + (size_t)__float_as_int(p[j].x) * 32) + c4);
#pragma unroll
        for (int j = 0; j < 8; ++j) {
            acc.x = fmaf(p[j].y, bf2f(v[j].x), acc.x);
            acc.y = fmaf(p[j].y, bf2f(v[j].y), acc.y);
            acc.z = fmaf(p[j].y, bf2f(v[j].z), acc.z);
            acc.w = fmaf(p[j].y, bf2f(v[j].w), acc.w);
        }
    }
    for (; k + 4 <= cn; k += 4) {
        float2 p[4];
#pragma unroll
        for (int j = 0; j < 4; ++j) p[j] = pp[k + j];
        ushort4 v[4];
#pragma unroll
        for (int j = 0; j < 4; ++j)
            v[j] = *((const ushort4*)(hb + (size_t)__float_as_int(p[j].x) * 32) + c4);
#pragma unroll
        for (int j = 0; j < 4; ++j) {
            acc.x = fmaf(p[j].y, bf2f(v[j].x), acc.x);
            acc.y = fmaf(p[j].y, bf2f(v[j].y), acc.y);
            acc.z = fmaf(p[j].y, bf2f(v[j].z), acc.z);
            acc.w = fmaf(p[j].y, bf2f(v[j].w), acc.w);
        }
    }
    for (; k < cn; ++k) {
        float2 p = pp[k];
        ushort4 v = *((const ushort4*)(hb + (size_t)__float_as_int(p.x) * 32) + c4);
        acc.x = fmaf(p.y, bf2f(v.x), acc.x);
        acc.y = fmaf(p.y, bf2f(v.y), acc.y);
        acc.z = fmaf(p.y, bf2f(v.z), acc.z);
        acc.w = fmaf(p.y, bf2f(v.w), acc.w);
    }
    if (FUSE) {
        int ln = tid >> 3;
        int cb = c4 * 4;
        srow[ln * 33 + cb + 0] = fmaxf(acc.x + bias[cb + 0], 0.0f);
        srow[ln * 33 + cb + 1] = fmaxf(acc.y + bias[cb + 1], 0.0f);
        srow[ln * 33 + cb + 2] = fmaxf(acc.z + bias[cb + 2], 0.0f);
        srow[ln * 33 + cb + 3] = fmaxf(acc.w + bias[cb + 3], 0.0f);
        __syncthreads();
        const float* rw = srow + ln * 33;
        float o0 = 0.f, o1 = 0.f, o2 = 0.f, o3 = 0.f;
#pragma unroll
        for (int kk = 0; kk < 32; ++kk) {
            float r = rw[kk];
            const float* wr = sW + kk * 32 + cb;
            o0 = fmaf(r, wr[0], o0);
            o1 = fmaf(r, wr[1], o1);
            o2 = fmaf(r, wr[2], o2);
            o3 = fmaf(r, wr[3], o3);
        }
        ushort4 ou;
        ou.x = f2bf(o0); ou.y = f2bf(o1); ou.z = f2bf(o2); ou.w = f2bf(o3);
        *((ushort4*)(hout + (size_t)n * 32) + c4) = ou;
    } else {
        aggout[t] = acc;
    }
}

// ---------- global mean pool + linear head + log_softmax ----------
__global__ __launch_bounds__(1024) void k_pool_head(const float* __restrict__ agg3,
                                                    const float* __restrict__ b3,
                                                    const int* __restrict__ batch,
                                                    const float* __restrict__ Wout,
                                                    const float* __restrict__ bout,
                                                    float* __restrict__ out) {
    int g = blockIdx.x;
    __shared__ int sb[2];
    if (threadIdx.x == 0) {
        int lo = 0, hi = NN;
        while (lo < hi) { int m = (lo + hi) >> 1; if (batch[m] < g) lo = m + 1; else hi = m; }
        sb[0] = lo;
        lo = 0; hi = NN;
        while (lo < hi) { int m = (lo + hi) >> 1; if (batch[m] < g + 1) lo = m + 1; else hi = m; }
        sb[1] = lo;
    }
    __syncthreads();
    int start = sb[0], end = sb[1];
    int c = threadIdx.x & 31, grp = threadIdx.x >> 5;
    float bc = b3[c];
    float acc = 0.0f;
    for (int n = start + grp; n < end; n += 32)
        acc += fmaxf(agg3[(size_t)n * 32 + c] + bc, 0.0f);
    __shared__ float red[32 * 32];
    red[grp * 32 + c] = acc;
    __syncthreads();
    __shared__ float pooled[32];
    if (threadIdx.x < 32) {
        float s = 0.0f;
#pragma unroll
        for (int gr = 0; gr < 32; ++gr) s += red[gr * 32 + threadIdx.x];
        pooled[threadIdx.x] = s / fmaxf((float)(end - start), 1.0f);
    }
    __syncthreads();
    __shared__ float slog[8];
    if (threadIdx.x < 8) {
        float l = bout[threadIdx.x];
#pragma unroll
        for (int k = 0; k < 32; ++k) l = fmaf(pooled[k], Wout[k * 8 + threadIdx.x], l);
        slog[threadIdx.x] = l;
    }
    __syncthreads();
    if (threadIdx.x < 8) {
        float m = slog[0];
#pragma unroll
        for (int i = 1; i < 8; ++i) m = fmaxf(m, slog[i]);
        float s = 0.0f;
#pragma unroll
        for (int i = 0; i < 8; ++i) s += expf(slog[i] - m);
        out[g * NC + threadIdx.x] = slog[threadIdx.x] - m - logf(s);
    }
}

extern "C" void kernel_launch(void* const* d_in, const int* in_sizes, int n_in,
                              void* d_out, int out_size, void* d_ws, size_t ws_size,
                              hipStream_t stream) {
    const float* x     = (const float*)d_in[0];
    const int*   eidx  = (const int*)d_in[1];
    const float* ew    = (const float*)d_in[2];
    const int*   batch = (const int*)d_in[3];
    const float* W1 = (const float*)d_in[4];
    const float* b1 = (const float*)d_in[5];
    const float* W2 = (const float*)d_in[6];
    const float* b2 = (const float*)d_in[7];
    const float* W3 = (const float*)d_in[8];
    const float* b3 = (const float*)d_in[9];
    const float* Wout = (const float*)d_in[10];
    const float* bout = (const float*)d_in[11];
    float* out = (float*)d_out;

    const int* row = eidx;        // sources
    const int* col = eidx + NE;   // targets

    // layout: A(f32 12.8MB) | B1(bf16 6.4MB) | B2(bf16 6.4MB) | pairs | dinv | cnt
    float* A = (float*)d_ws;
    unsigned short* B1 = (unsigned short*)(A + (size_t)NN * HD);
    unsigned short* B2 = B1 + (size_t)NN * HD;
    float2* pairs = (float2*)(B2 + (size_t)NN * HD);
    size_t fixed = (size_t)NN * HD * 4 + (size_t)NN * HD * 2 * 2 + (size_t)NN * 4 * 2;
    int cap = (ws_size >= fixed + (size_t)NN * 64 * sizeof(float2)) ? 64 : 48;
    float* dinv = (float*)(pairs + (size_t)NN * cap);
    int* cnt = (int*)(dinv + NN);

    hipMemsetAsync(cnt, 0, NN * sizeof(int), stream);
    k_fill<<<(NE + 255) / 256, 256, 0, stream>>>(row, col, ew, cnt, pairs, cap);
    k_node_dinv<<<NORM_BLOCKS, 256, 0, stream>>>(cnt, pairs, dinv, cap);
    k_norm_gemm0<<<NORM_BLOCKS + GEMM0_BLOCKS, 256, 0, stream>>>(cnt, dinv, pairs, cap,
                                                                 x, W1, B1);
    k_gather<true><<<NORM_BLOCKS, 256, 0, stream>>>(B1, cnt, dinv, pairs, cap,
                                                    b1, W2, B2, nullptr);
    k_gather<true><<<NORM_BLOCKS, 256, 0, stream>>>(B2, cnt, dinv, pairs, cap,
                                                    b2, W3, B1, nullptr);
    k_gather<false><<<NORM_BLOCKS, 256, 0, stream>>>(B1, cnt, dinv, pairs, cap,
                                                     nullptr, nullptr, nullptr, (float4*)A);
    k_pool_head<<<NG, 1024, 0, stream>>>(A, b3, batch, Wout, bout, out);
}

// Round 6
// 183.848 us; speedup vs baseline: 11.6197x; 1.4087x over previous
//
#include <hip/hip_runtime.h>
#include <math.h>

#define NN 100000
#define NE 1600000
#define HD 32
#define NG 64
#define NC 8

#define P 256         // partitions
#define PART 391      // nodes per partition; 391*256 = 100096 >= NN
#define SCAP 7000     // staging capacity per partition (Poisson(6256), +9 sigma)
#define CH 2048       // edges per k_bin block
#define NBIN ((NE + CH - 1) / CH)
#define NORM_BLOCKS (NN * 8 / 256)   // 3125
#define GEMM0_BLOCKS (NN / 8)        // 12500

__device__ __forceinline__ float bf2f(unsigned short u) {
    return __uint_as_float(((unsigned int)u) << 16);
}
__device__ __forceinline__ unsigned short f2bf(float f) {
    unsigned int b = __float_as_uint(f);
    b = (b + 0x7FFFu + ((b >> 16) & 1u)) >> 16;  // RNE
    return (unsigned short)b;
}

// ---------- phase 1: bin edges into col-range partitions ----------
// staging entry: x = col_lo | (row << 9)  (col_lo < 391 < 512), y = w bits
__global__ __launch_bounds__(256) void k_bin(const int* __restrict__ row,
                                             const int* __restrict__ col,
                                             const float* __restrict__ w,
                                             int* __restrict__ pcnt,
                                             uint2* __restrict__ staging) {
    __shared__ int hist[P];
    __shared__ int base_[P];
    int tid = threadIdx.x;
    int e0 = blockIdx.x * CH;
    hist[tid] = 0;
    __syncthreads();
    for (int i = tid; i < CH; i += 256) {
        int e = e0 + i;
        if (e < NE) atomicAdd(&hist[(unsigned)col[e] / PART], 1);
    }
    __syncthreads();
    int h = hist[tid];
    base_[tid] = h ? atomicAdd(&pcnt[tid], h) : 0;
    __syncthreads();
    hist[tid] = 0;
    __syncthreads();
    for (int i = tid; i < CH; i += 256) {
        int e = e0 + i;
        if (e < NE) {
            int c = col[e];
            int p = (unsigned)c / PART;
            int pos = base_[p] + atomicAdd(&hist[p], 1);
            uint2 v;
            v.x = (unsigned)(c - p * PART) | ((unsigned)row[e] << 9);
            v.y = __float_as_uint(w[e]);
            staging[(size_t)p * SCAP + pos] = v;
        }
    }
}

// ---------- exclusive scan of partition counts ----------
__global__ __launch_bounds__(256) void k_pscan(const int* __restrict__ pcnt,
                                               int* __restrict__ pbase) {
    __shared__ int s[P];
    int tid = threadIdx.x;
    int v = pcnt[tid];
    s[tid] = v;
    __syncthreads();
#pragma unroll
    for (int d = 1; d < P; d <<= 1) {
        int t = (tid >= d) ? s[tid - d] : 0;
        __syncthreads();
        s[tid] += t;
        __syncthreads();
    }
    pbase[tid] = s[tid] - v;
}

// ---------- phase 2: per-partition CSR build + dinv (all atomics in LDS) ----------
__global__ __launch_bounds__(256) void k_build(const int* __restrict__ pcnt,
                                               const int* __restrict__ pbase,
                                               const uint2* __restrict__ staging,
                                               float2* __restrict__ pairs,
                                               int* __restrict__ off,
                                               int* __restrict__ cntg,
                                               float* __restrict__ dinv) {
    __shared__ int cnt_l[PART];
    __shared__ float wsum[PART];
    __shared__ int sc[PART];
    __shared__ int cur[PART];
    int p = blockIdx.x, tid = threadIdx.x;
    int m = pcnt[p], pb = pbase[p];
    for (int i = tid; i < PART; i += 256) { cnt_l[i] = 0; wsum[i] = 0.0f; }
    __syncthreads();
    const uint2* st = staging + (size_t)p * SCAP;
    for (int i = tid; i < m; i += 256) {
        uint2 v = st[i];
        int cl = v.x & 511;
        atomicAdd(&cnt_l[cl], 1);
        atomicAdd(&wsum[cl], __uint_as_float(v.y));
    }
    __syncthreads();
    for (int i = tid; i < PART; i += 256) sc[i] = cnt_l[i];
    __syncthreads();
    // inclusive Hillis-Steele over PART elements, 2 per thread
    int i0 = tid, i1 = tid + 256;
#pragma unroll
    for (int d = 1; d < 512; d <<= 1) {
        int t0 = 0, t1 = 0;
        if (i0 < PART && i0 >= d) t0 = sc[i0 - d];
        if (i1 < PART && i1 >= d) t1 = sc[i1 - d];
        __syncthreads();
        if (i0 < PART) sc[i0] += t0;
        if (i1 < PART) sc[i1] += t1;
        __syncthreads();
    }
    for (int i = tid; i < PART; i += 256) {
        int excl = sc[i] - cnt_l[i];
        cur[i] = excl;
        int n = p * PART + i;
        if (n < NN) {
            off[n] = pb + excl;
            cntg[n] = cnt_l[i];
            dinv[n] = rsqrtf(1.0f + wsum[i]);
        }
    }
    __syncthreads();
    for (int i = tid; i < m; i += 256) {
        uint2 v = st[i];
        int cl = v.x & 511;
        int r = (int)(v.x >> 9);
        int pos = atomicAdd(&cur[cl], 1);
        pairs[pb + pos] = make_float2(__int_as_float(r), __uint_as_float(v.y));
    }
}

// ---------- heterogeneous: normalize pairs  ||  h1 = x @ W1 (bf16 out) ----------
__global__ __launch_bounds__(256) void k_norm_gemm0(const int* __restrict__ off,
                                                    const int* __restrict__ cntg,
                                                    const float* __restrict__ dinv,
                                                    float2* __restrict__ pairs,
                                                    const float* __restrict__ x,
                                                    const float* __restrict__ W1,
                                                    unsigned short* __restrict__ h1) {
    __shared__ float sW[32 * 32];
    __shared__ float sX[8 * 32];
    int tid = threadIdx.x;
    if (blockIdx.x < NORM_BLOCKS) {
        int t = blockIdx.x * 256 + tid;
        int n = t >> 3, q = t & 7;
        int cn = cntg[n];
        float dn = dinv[n];
        float2* pp = pairs + off[n];
        for (int k = q; k < cn; k += 8) {
            float2 p = pp[k];
            p.y = dinv[__float_as_int(p.x)] * p.y * dn;
            pp[k] = p;
        }
    } else {
        int base = (blockIdx.x - NORM_BLOCKS) * 8;
        ((float4*)sW)[tid] = ((const float4*)W1)[tid];
        if (tid < 64) ((float4*)sX)[tid] = ((const float4*)(x + (size_t)base * 32))[tid];
        __syncthreads();
        int c = tid & 31, nl = tid >> 5;
        float acc = 0.0f;
#pragma unroll
        for (int k = 0; k < 32; ++k) acc = fmaf(sX[nl * 32 + k], sW[k * 32 + c], acc);
        h1[(size_t)(base + nl) * 32 + c] = f2bf(acc);
    }
}

// ---------- gather (bf16 h), optionally fused with next GEMM ----------
template <bool FUSE>
__global__ __launch_bounds__(256) void k_gather(const unsigned short* __restrict__ hb,
                                                const int* __restrict__ off,
                                                const int* __restrict__ cntg,
                                                const float* __restrict__ dinv,
                                                const float2* __restrict__ pairs,
                                                const float* __restrict__ bias,
                                                const float* __restrict__ Wn,
                                                unsigned short* __restrict__ hout,
                                                float4* __restrict__ aggout) {
    __shared__ float sW[32 * 32];
    __shared__ float srow[32 * 33];
    int tid = threadIdx.x;
    if (FUSE) ((float4*)sW)[tid] = ((const float4*)Wn)[tid];
    int t = blockIdx.x * 256 + tid;  // NN*8 exact
    int n = t >> 3, c4 = t & 7;
    int cn = cntg[n];
    const float2* pp = pairs + off[n];
    float di = dinv[n];
    float sl = di * di;
    ushort4 hu = *((const ushort4*)(hb + (size_t)n * 32) + c4);
    float4 acc = make_float4(sl * bf2f(hu.x), sl * bf2f(hu.y),
                             sl * bf2f(hu.z), sl * bf2f(hu.w));
    int k = 0;
    for (; k + 8 <= cn; k += 8) {
        float2 p[8];
#pragma unroll
        for (int j = 0; j < 8; ++j) p[j] = pp[k + j];
        ushort4 v[8];
#pragma unroll
        for (int j = 0; j < 8; ++j)
            v[j] = *((const ushort4*)(hb + (size_t)__float_as_int(p[j].x) * 32) + c4);
#pragma unroll
        for (int j = 0; j < 8; ++j) {
            acc.x = fmaf(p[j].y, bf2f(v[j].x), acc.x);
            acc.y = fmaf(p[j].y, bf2f(v[j].y), acc.y);
            acc.z = fmaf(p[j].y, bf2f(v[j].z), acc.z);
            acc.w = fmaf(p[j].y, bf2f(v[j].w), acc.w);
        }
    }
    for (; k + 4 <= cn; k += 4) {
        float2 p[4];
#pragma unroll
        for (int j = 0; j < 4; ++j) p[j] = pp[k + j];
        ushort4 v[4];
#pragma unroll
        for (int j = 0; j < 4; ++j)
            v[j] = *((const ushort4*)(hb + (size_t)__float_as_int(p[j].x) * 32) + c4);
#pragma unroll
        for (int j = 0; j < 4; ++j) {
            acc.x = fmaf(p[j].y, bf2f(v[j].x), acc.x);
            acc.y = fmaf(p[j].y, bf2f(v[j].y), acc.y);
            acc.z = fmaf(p[j].y, bf2f(v[j].z), acc.z);
            acc.w = fmaf(p[j].y, bf2f(v[j].w), acc.w);
        }
    }
    for (; k < cn; ++k) {
        float2 p = pp[k];
        ushort4 v = *((const ushort4*)(hb + (size_t)__float_as_int(p.x) * 32) + c4);
        acc.x = fmaf(p.y, bf2f(v.x), acc.x);
        acc.y = fmaf(p.y, bf2f(v.y), acc.y);
        acc.z = fmaf(p.y, bf2f(v.z), acc.z);
        acc.w = fmaf(p.y, bf2f(v.w), acc.w);
    }
    if (FUSE) {
        int ln = tid >> 3;
        int cb = c4 * 4;
        srow[ln * 33 + cb + 0] = fmaxf(acc.x + bias[cb + 0], 0.0f);
        srow[ln * 33 + cb + 1] = fmaxf(acc.y + bias[cb + 1], 0.0f);
        srow[ln * 33 + cb + 2] = fmaxf(acc.z + bias[cb + 2], 0.0f);
        srow[ln * 33 + cb + 3] = fmaxf(acc.w + bias[cb + 3], 0.0f);
        __syncthreads();
        const float* rw = srow + ln * 33;
        float o0 = 0.f, o1 = 0.f, o2 = 0.f, o3 = 0.f;
#pragma unroll
        for (int kk = 0; kk < 32; ++kk) {
            float r = rw[kk];
            const float* wr = sW + kk * 32 + cb;
            o0 = fmaf(r, wr[0], o0);
            o1 = fmaf(r, wr[1], o1);
            o2 = fmaf(r, wr[2], o2);
            o3 = fmaf(r, wr[3], o3);
        }
        ushort4 ou;
        ou.x = f2bf(o0); ou.y = f2bf(o1); ou.z = f2bf(o2); ou.w = f2bf(o3);
        *((ushort4*)(hout + (size_t)n * 32) + c4) = ou;
    } else {
        aggout[t] = acc;
    }
}

// ---------- global mean pool + linear head + log_softmax ----------
__global__ __launch_bounds__(1024) void k_pool_head(const float* __restrict__ agg3,
                                                    const float* __restrict__ b3,
                                                    const int* __restrict__ batch,
                                                    const float* __restrict__ Wout,
                                                    const float* __restrict__ bout,
                                                    float* __restrict__ out) {
    int g = blockIdx.x;
    __shared__ int sb[2];
    if (threadIdx.x == 0) {
        int lo = 0, hi = NN;
        while (lo < hi) { int m = (lo + hi) >> 1; if (batch[m] < g) lo = m + 1; else hi = m; }
        sb[0] = lo;
        lo = 0; hi = NN;
        while (lo < hi) { int m = (lo + hi) >> 1; if (batch[m] < g + 1) lo = m + 1; else hi = m; }
        sb[1] = lo;
    }
    __syncthreads();
    int start = sb[0], end = sb[1];
    int c = threadIdx.x & 31, grp = threadIdx.x >> 5;
    float bc = b3[c];
    float acc = 0.0f;
    for (int n = start + grp; n < end; n += 32)
        acc += fmaxf(agg3[(size_t)n * 32 + c] + bc, 0.0f);
    __shared__ float red[32 * 32];
    red[grp * 32 + c] = acc;
    __syncthreads();
    __shared__ float pooled[32];
    if (threadIdx.x < 32) {
        float s = 0.0f;
#pragma unroll
        for (int gr = 0; gr < 32; ++gr) s += red[gr * 32 + threadIdx.x];
        pooled[threadIdx.x] = s / fmaxf((float)(end - start), 1.0f);
    }
    __syncthreads();
    __shared__ float slog[8];
    if (threadIdx.x < 8) {
        float l = bout[threadIdx.x];
#pragma unroll
        for (int k = 0; k < 32; ++k) l = fmaf(pooled[k], Wout[k * 8 + threadIdx.x], l);
        slog[threadIdx.x] = l;
    }
    __syncthreads();
    if (threadIdx.x < 8) {
        float m = slog[0];
#pragma unroll
        for (int i = 1; i < 8; ++i) m = fmaxf(m, slog[i]);
        float s = 0.0f;
#pragma unroll
        for (int i = 0; i < 8; ++i) s += expf(slog[i] - m);
        out[g * NC + threadIdx.x] = slog[threadIdx.x] - m - logf(s);
    }
}

extern "C" void kernel_launch(void* const* d_in, const int* in_sizes, int n_in,
                              void* d_out, int out_size, void* d_ws, size_t ws_size,
                              hipStream_t stream) {
    const float* x     = (const float*)d_in[0];
    const int*   eidx  = (const int*)d_in[1];
    const float* ew    = (const float*)d_in[2];
    const int*   batch = (const int*)d_in[3];
    const float* W1 = (const float*)d_in[4];
    const float* b1 = (const float*)d_in[5];
    const float* W2 = (const float*)d_in[6];
    const float* b2 = (const float*)d_in[7];
    const float* W3 = (const float*)d_in[8];
    const float* b3 = (const float*)d_in[9];
    const float* Wout = (const float*)d_in[10];
    const float* bout = (const float*)d_in[11];
    float* out = (float*)d_out;

    const int* row = eidx;        // sources
    const int* col = eidx + NE;   // targets

    // layout: A f32 | B1 bf16 | B2 bf16 | pairs(CSR) | staging | dinv | off | cnt | pcnt | pbase
    float* A = (float*)d_ws;                                     // 12.8 MB
    unsigned short* B1 = (unsigned short*)(A + (size_t)NN * HD); // 6.4 MB
    unsigned short* B2 = B1 + (size_t)NN * HD;                   // 6.4 MB
    float2* pairs = (float2*)(B2 + (size_t)NN * HD);             // 12.8 MB
    uint2* staging = (uint2*)(pairs + NE);                       // 14.3 MB
    float* dinv = (float*)(staging + (size_t)P * SCAP);          // 0.4 MB
    int* off  = (int*)(dinv + NN);                               // 0.4 MB
    int* cntg = off + NN;                                        // 0.4 MB
    int* pcnt = cntg + NN;                                       // 1 KB
    int* pbase = pcnt + P;

    hipMemsetAsync(pcnt, 0, P * sizeof(int), stream);
    k_bin<<<NBIN, 256, 0, stream>>>(row, col, ew, pcnt, staging);
    k_pscan<<<1, 256, 0, stream>>>(pcnt, pbase);
    k_build<<<P, 256, 0, stream>>>(pcnt, pbase, staging, pairs, off, cntg, dinv);
    k_norm_gemm0<<<NORM_BLOCKS + GEMM0_BLOCKS, 256, 0, stream>>>(off, cntg, dinv, pairs,
                                                                 x, W1, B1);
    k_gather<true><<<NORM_BLOCKS, 256, 0, stream>>>(B1, off, cntg, dinv, pairs,
                                                    b1, W2, B2, nullptr);
    k_gather<true><<<NORM_BLOCKS, 256, 0, stream>>>(B2, off, cntg, dinv, pairs,
                                                    b2, W3, B1, nullptr);
    k_gather<false><<<NORM_BLOCKS, 256, 0, stream>>>(B1, off, cntg, dinv, pairs,
                                                     nullptr, nullptr, nullptr, (float4*)A);
    k_pool_head<<<NG, 1024, 0, stream>>>(A, b3, batch, Wout, bout, out);
}

// Round 7
// 168.669 us; speedup vs baseline: 12.6654x; 1.0900x over previous
//
#include <hip/hip_runtime.h>
#include <math.h>

#define NN 100000
#define NE 1600000
#define HD 32
#define NG 64
#define NC 8

#define P 256         // partitions
#define PART 391      // nodes per partition; 391*256 = 100096 >= NN
#define SCAP 7000     // staging capacity per partition (Poisson(6250), +9 sigma)
#define CH 4096       // edges per k_bin block
#define NBIN ((NE + CH - 1) / CH)    // 391
#define NORM_BLOCKS (NN * 8 / 256)   // 3125 (gather grid)
#define GEMM0_BLOCKS (NN / 8)        // 12500

__device__ __forceinline__ float bf2f(unsigned short u) {
    return __uint_as_float(((unsigned int)u) << 16);
}
__device__ __forceinline__ unsigned short f2bf(float f) {
    unsigned int b = __float_as_uint(f);
    b = (b + 0x7FFFu + ((b >> 16) & 1u)) >> 16;  // RNE
    return (unsigned short)b;
}

// ---------- phase 1: bin edges into col-range partitions ----------
// staging entry: x = col_lo | (row << 9)  (col_lo < 391 < 512), y = w bits
__global__ __launch_bounds__(256) void k_bin(const int* __restrict__ row,
                                             const int* __restrict__ col,
                                             const float* __restrict__ w,
                                             int* __restrict__ pcnt,
                                             uint2* __restrict__ staging) {
    __shared__ int scol[CH];   // 16 KB
    __shared__ int hist[P];
    __shared__ int base_[P];
    int tid = threadIdx.x;
    int e0 = blockIdx.x * CH;
    int nrem = min(CH, NE - e0);
    hist[tid] = 0;
    __syncthreads();
    for (int i = tid; i < nrem; i += 256) {
        int c = col[e0 + i];
        scol[i] = c;
        atomicAdd(&hist[(unsigned)c / PART], 1);
    }
    __syncthreads();
    int h = hist[tid];
    base_[tid] = h ? atomicAdd(&pcnt[tid], h) : 0;
    __syncthreads();
    hist[tid] = 0;
    __syncthreads();
    for (int i = tid; i < nrem; i += 256) {
        int c = scol[i];
        int p = (unsigned)c / PART;
        int pos = base_[p] + atomicAdd(&hist[p], 1);
        uint2 v;
        v.x = (unsigned)(c - p * PART) | ((unsigned)row[e0 + i] << 9);
        v.y = __float_as_uint(w[e0 + i]);
        staging[(size_t)p * SCAP + pos] = v;
    }
}

// ---------- phase 2a (fused with gemm0): per-partition counts + dinv + CSR offsets ----------
__global__ __launch_bounds__(256) void k_csrA_gemm0(const int* __restrict__ pcnt,
                                                    const int* __restrict__ pbase,
                                                    const uint2* __restrict__ staging,
                                                    int* __restrict__ off,
                                                    int* __restrict__ cntg,
                                                    float* __restrict__ dinv,
                                                    const float* __restrict__ x,
                                                    const float* __restrict__ W1,
                                                    unsigned short* __restrict__ h1) {
    int tid = threadIdx.x;
    if (blockIdx.x < P) {
        __shared__ int cnt_l[PART];
        __shared__ float wsum[PART];
        __shared__ int sc[PART];
        int p = blockIdx.x;
        int m = pcnt[p], pb = pbase[p];
        for (int i = tid; i < PART; i += 256) { cnt_l[i] = 0; wsum[i] = 0.0f; }
        __syncthreads();
        const uint2* st = staging + (size_t)p * SCAP;
        for (int i = tid; i < m; i += 256) {
            uint2 v = st[i];
            int cl = v.x & 511;
            atomicAdd(&cnt_l[cl], 1);
            atomicAdd(&wsum[cl], __uint_as_float(v.y));
        }
        __syncthreads();
        for (int i = tid; i < PART; i += 256) sc[i] = cnt_l[i];
        __syncthreads();
        int i0 = tid, i1 = tid + 256;
#pragma unroll
        for (int d = 1; d < 512; d <<= 1) {
            int t0 = 0, t1 = 0;
            if (i0 < PART && i0 >= d) t0 = sc[i0 - d];
            if (i1 < PART && i1 >= d) t1 = sc[i1 - d];
            __syncthreads();
            if (i0 < PART) sc[i0] += t0;
            if (i1 < PART) sc[i1] += t1;
            __syncthreads();
        }
        for (int i = tid; i < PART; i += 256) {
            int n = p * PART + i;
            if (n < NN) {
                off[n] = pb + sc[i] - cnt_l[i];
                cntg[n] = cnt_l[i];
                dinv[n] = rsqrtf(1.0f + wsum[i]);
            }
        }
    } else {
        __shared__ float sW[32 * 32];
        __shared__ float sX[8 * 32];
        int base = (blockIdx.x - P) * 8;
        ((float4*)sW)[tid] = ((const float4*)W1)[tid];
        if (tid < 64) ((float4*)sX)[tid] = ((const float4*)(x + (size_t)base * 32))[tid];
        __syncthreads();
        int c = tid & 31, nl = tid >> 5;
        float acc = 0.0f;
#pragma unroll
        for (int k = 0; k < 32; ++k) acc = fmaf(sX[nl * 32 + k], sW[k * 32 + c], acc);
        h1[(size_t)(base + nl) * 32 + c] = f2bf(acc);
    }
}

// ---------- phase 2b: write final normalized pairs (LDS cursors, batched dinv reads) ----------
__global__ __launch_bounds__(512) void k_csr_b(const int* __restrict__ pcnt,
                                               const uint2* __restrict__ staging,
                                               const int* __restrict__ off,
                                               const float* __restrict__ dinv,
                                               float2* __restrict__ pairs) {
    __shared__ int cur[PART];
    __shared__ float sdc[PART];
    int p = blockIdx.x, tid = threadIdx.x;
    int m = pcnt[p];
    const uint2* st = staging + (size_t)p * SCAP;
    for (int i = tid; i < PART; i += 512) {
        int n = p * PART + i;
        cur[i] = (n < NN) ? off[n] : 0;
        sdc[i] = (n < NN) ? dinv[n] : 0.0f;
    }
    __syncthreads();
    for (int ib = tid; ib < m; ib += 512 * 4) {
        uint2 v[4];
        float dr[4];
#pragma unroll
        for (int j = 0; j < 4; ++j) {
            int i = ib + j * 512;
            if (i < m) v[j] = st[i];
        }
#pragma unroll
        for (int j = 0; j < 4; ++j) {
            int i = ib + j * 512;
            if (i < m) dr[j] = dinv[v[j].x >> 9];
        }
#pragma unroll
        for (int j = 0; j < 4; ++j) {
            int i = ib + j * 512;
            if (i < m) {
                int cl = v[j].x & 511;
                int pos = atomicAdd(&cur[cl], 1);
                float y = dr[j] * __uint_as_float(v[j].y) * sdc[cl];
                pairs[pos] = make_float2(__int_as_float((int)(v[j].x >> 9)), y);
            }
        }
    }
}

// ---------- gather (bf16 h): MODE 0 = fuse next GEMM, MODE 1 = final relu(agg+bias) ----------
template <int MODE>
__global__ __launch_bounds__(256) void k_gather(const unsigned short* __restrict__ hb,
                                                const int* __restrict__ off,
                                                const int* __restrict__ cntg,
                                                const float* __restrict__ dinv,
                                                const float2* __restrict__ pairs,
                                                const float* __restrict__ bias,
                                                const float* __restrict__ Wn,
                                                unsigned short* __restrict__ hout) {
    __shared__ float sW[32 * 32];
    __shared__ float srow[32 * 33];
    int tid = threadIdx.x;
    if (MODE == 0) ((float4*)sW)[tid] = ((const float4*)Wn)[tid];
    int t = blockIdx.x * 256 + tid;  // NN*8 exact
    int n = t >> 3, c4 = t & 7;
    int cn = cntg[n];
    const float2* pp = pairs + off[n];
    float di = dinv[n];
    float sl = di * di;
    ushort4 hu = *((const ushort4*)(hb + (size_t)n * 32) + c4);
    float4 acc = make_float4(sl * bf2f(hu.x), sl * bf2f(hu.y),
                             sl * bf2f(hu.z), sl * bf2f(hu.w));
    int k = 0;
    for (; k + 8 <= cn; k += 8) {
        float2 p[8];
#pragma unroll
        for (int j = 0; j < 8; ++j) p[j] = pp[k + j];
        ushort4 v[8];
#pragma unroll
        for (int j = 0; j < 8; ++j)
            v[j] = *((const ushort4*)(hb + (size_t)__float_as_int(p[j].x) * 32) + c4);
#pragma unroll
        for (int j = 0; j < 8; ++j) {
            acc.x = fmaf(p[j].y, bf2f(v[j].x), acc.x);
            acc.y = fmaf(p[j].y, bf2f(v[j].y), acc.y);
            acc.z = fmaf(p[j].y, bf2f(v[j].z), acc.z);
            acc.w = fmaf(p[j].y, bf2f(v[j].w), acc.w);
        }
    }
    for (; k + 4 <= cn; k += 4) {
        float2 p[4];
#pragma unroll
        for (int j = 0; j < 4; ++j) p[j] = pp[k + j];
        ushort4 v[4];
#pragma unroll
        for (int j = 0; j < 4; ++j)
            v[j] = *((const ushort4*)(hb + (size_t)__float_as_int(p[j].x) * 32) + c4);
#pragma unroll
        for (int j = 0; j < 4; ++j) {
            acc.x = fmaf(p[j].y, bf2f(v[j].x), acc.x);
            acc.y = fmaf(p[j].y, bf2f(v[j].y), acc.y);
            acc.z = fmaf(p[j].y, bf2f(v[j].z), acc.z);
            acc.w = fmaf(p[j].y, bf2f(v[j].w), acc.w);
        }
    }
    for (; k < cn; ++k) {
        float2 p = pp[k];
        ushort4 v = *((const ushort4*)(hb + (size_t)__float_as_int(p.x) * 32) + c4);
        acc.x = fmaf(p.y, bf2f(v.x), acc.x);
        acc.y = fmaf(p.y, bf2f(v.y), acc.y);
        acc.z = fmaf(p.y, bf2f(v.z), acc.z);
        acc.w = fmaf(p.y, bf2f(v.w), acc.w);
    }
    int cb = c4 * 4;
    if (MODE == 0) {
        int ln = tid >> 3;
        srow[ln * 33 + cb + 0] = fmaxf(acc.x + bias[cb + 0], 0.0f);
        srow[ln * 33 + cb + 1] = fmaxf(acc.y + bias[cb + 1], 0.0f);
        srow[ln * 33 + cb + 2] = fmaxf(acc.z + bias[cb + 2], 0.0f);
        srow[ln * 33 + cb + 3] = fmaxf(acc.w + bias[cb + 3], 0.0f);
        __syncthreads();
        const float* rw = srow + ln * 33;
        float o0 = 0.f, o1 = 0.f, o2 = 0.f, o3 = 0.f;
#pragma unroll
        for (int kk = 0; kk < 32; ++kk) {
            float r = rw[kk];
            const float* wr = sW + kk * 32 + cb;
            o0 = fmaf(r, wr[0], o0);
            o1 = fmaf(r, wr[1], o1);
            o2 = fmaf(r, wr[2], o2);
            o3 = fmaf(r, wr[3], o3);
        }
        ushort4 ou;
        ou.x = f2bf(o0); ou.y = f2bf(o1); ou.z = f2bf(o2); ou.w = f2bf(o3);
        *((ushort4*)(hout + (size_t)n * 32) + c4) = ou;
    } else {
        ushort4 ou;
        ou.x = f2bf(fmaxf(acc.x + bias[cb + 0], 0.0f));
        ou.y = f2bf(fmaxf(acc.y + bias[cb + 1], 0.0f));
        ou.z = f2bf(fmaxf(acc.z + bias[cb + 2], 0.0f));
        ou.w = f2bf(fmaxf(acc.w + bias[cb + 3], 0.0f));
        *((ushort4*)(hout + (size_t)n * 32) + c4) = ou;
    }
}

// ---------- global mean pool (bf16 in, already relu+bias) + head + log_softmax ----------
__global__ __launch_bounds__(1024) void k_pool_head(const unsigned short* __restrict__ h3,
                                                    const int* __restrict__ batch,
                                                    const float* __restrict__ Wout,
                                                    const float* __restrict__ bout,
                                                    float* __restrict__ out) {
    int g = blockIdx.x;
    __shared__ int sb[2];
    if (threadIdx.x == 0) {
        int lo = 0, hi = NN;
        while (lo < hi) { int m = (lo + hi) >> 1; if (batch[m] < g) lo = m + 1; else hi = m; }
        sb[0] = lo;
        lo = 0; hi = NN;
        while (lo < hi) { int m = (lo + hi) >> 1; if (batch[m] < g + 1) lo = m + 1; else hi = m; }
        sb[1] = lo;
    }
    __syncthreads();
    int start = sb[0], end = sb[1];
    int c = threadIdx.x & 31, grp = threadIdx.x >> 5;
    float acc = 0.0f;
    for (int n = start + grp; n < end; n += 32)
        acc += bf2f(h3[(size_t)n * 32 + c]);
    __shared__ float red[32 * 32];
    red[grp * 32 + c] = acc;
    __syncthreads();
    __shared__ float pooled[32];
    if (threadIdx.x < 32) {
        float s = 0.0f;
#pragma unroll
        for (int gr = 0; gr < 32; ++gr) s += red[gr * 32 + threadIdx.x];
        pooled[threadIdx.x] = s / fmaxf((float)(end - start), 1.0f);
    }
    __syncthreads();
    __shared__ float slog[8];
    if (threadIdx.x < 8) {
        float l = bout[threadIdx.x];
#pragma unroll
        for (int k = 0; k < 32; ++k) l = fmaf(pooled[k], Wout[k * 8 + threadIdx.x], l);
        slog[threadIdx.x] = l;
    }
    __syncthreads();
    if (threadIdx.x < 8) {
        float m = slog[0];
#pragma unroll
        for (int i = 1; i < 8; ++i) m = fmaxf(m, slog[i]);
        float s = 0.0f;
#pragma unroll
        for (int i = 0; i < 8; ++i) s += expf(slog[i] - m);
        out[g * NC + threadIdx.x] = slog[threadIdx.x] - m - logf(s);
    }
}

extern "C" void kernel_launch(void* const* d_in, const int* in_sizes, int n_in,
                              void* d_out, int out_size, void* d_ws, size_t ws_size,
                              hipStream_t stream) {
    const float* x     = (const float*)d_in[0];
    const int*   eidx  = (const int*)d_in[1];
    const float* ew    = (const float*)d_in[2];
    const int*   batch = (const int*)d_in[3];
    const float* W1 = (const float*)d_in[4];
    const float* b1 = (const float*)d_in[5];
    const float* W2 = (const float*)d_in[6];
    const float* b2 = (const float*)d_in[7];
    const float* W3 = (const float*)d_in[8];
    const float* b3 = (const float*)d_in[9];
    const float* Wout = (const float*)d_in[10];
    const float* bout = (const float*)d_in[11];
    float* out = (float*)d_out;

    const int* row = eidx;        // sources
    const int* col = eidx + NE;   // targets

    // layout: B1 bf16 | B2 bf16 | pairs(CSR) | staging | dinv | off | cntg | pcnt | pbase
    unsigned short* B1 = (unsigned short*)d_ws;                  // 6.4 MB
    unsigned short* B2 = B1 + (size_t)NN * HD;                   // 6.4 MB
    float2* pairs = (float2*)(B2 + (size_t)NN * HD);             // 12.8 MB
    uint2* staging = (uint2*)(pairs + NE);                       // 14.3 MB
    float* dinv = (float*)(staging + (size_t)P * SCAP);          // 0.4 MB
    int* off  = (int*)(dinv + NN);                               // 0.4 MB
    int* cntg = off + NN;                                        // 0.4 MB
    int* pcnt = cntg + NN;                                       // 1 KB
    int* pbase = pcnt + P;

    hipMemsetAsync(pcnt, 0, P * sizeof(int), stream);
    k_bin<<<NBIN, 256, 0, stream>>>(row, col, ew, pcnt, staging);
    // exclusive scan of P=256 partition counts, single block
    // (reuse k_pscan logic inline via a tiny lambda-style kernel)
    {
        struct L { static __global__ void scan(const int* pc, int* pb) {
            __shared__ int s[P];
            int tid = threadIdx.x;
            int v = pc[tid];
            s[tid] = v;
            __syncthreads();
#pragma unroll
            for (int d = 1; d < P; d <<= 1) {
                int t = (tid >= d) ? s[tid - d] : 0;
                __syncthreads();
                s[tid] += t;
                __syncthreads();
            }
            pb[tid] = s[tid] - v;
        } };
        hipLaunchKernelGGL(L::scan, dim3(1), dim3(P), 0, stream, pcnt, pbase);
    }
    k_csrA_gemm0<<<P + GEMM0_BLOCKS, 256, 0, stream>>>(pcnt, pbase, staging,
                                                       off, cntg, dinv, x, W1, B1);
    k_csr_b<<<P, 512, 0, stream>>>(pcnt, staging, off, dinv, pairs);
    k_gather<0><<<NORM_BLOCKS, 256, 0, stream>>>(B1, off, cntg, dinv, pairs, b1, W2, B2);
    k_gather<0><<<NORM_BLOCKS, 256, 0, stream>>>(B2, off, cntg, dinv, pairs, b2, W3, B1);
    k_gather<1><<<NORM_BLOCKS, 256, 0, stream>>>(B1, off, cntg, dinv, pairs, b3, nullptr, B2);
    k_pool_head<<<NG, 1024, 0, stream>>>(B2, batch, Wout, bout, out);
}